// Round 16
// baseline (89.191 us; speedup 1.0000x reference)
//
#include <hip/hip_runtime.h>

typedef unsigned int uint;
typedef __attribute__((ext_vector_type(8))) short bf16x8;   // MFMA A/B frag (4 VGPR)
typedef __attribute__((ext_vector_type(4))) float f32x4;    // MFMA C/D frag

#define B_ 2
#define C_ 128
#define H_ 96
#define W_ 96
#define HEADS_ 4
#define HD_ 32
#define M_ 16
#define WIN_ 7
#define PAD_ 3
#define N_ (H_*W_)              // 9216
#define HP_ (H_+2*PAD_)         // 102
#define HP2_ (HP_*HP_)          // 10404
#define TILE_ 8                 // attn tile is 8x8 pixels

static __device__ __forceinline__ uint f2bf(float f) {
    uint u = __float_as_uint(f);
    u = (u + 0x7fffu + ((u >> 16) & 1u)) >> 16;   // RNE to bf16 (integer, mode-independent)
    return u & 0xffffu;
}
static __device__ __forceinline__ uint pack2(float a, float b) {
    return f2bf(a) | (f2bf(b) << 16);
}

// LDS word swizzle for row-major [row][*] uint tiles (G4). XOR is a multiple
// of 4 so b128 (4-uint) groups stay contiguous; pairs (b64) also preserved.
#define SWZ(row, c2) ((c2) ^ (((row) & 7) << 2))

union U4 { uint u[4]; uint4 u4; bf16x8 v; };

// ---------------------------------------------------------------------------
// KVp layout (head-major, K/V interleaved, bf16 pairs):
//   KVp[((b*HEADS+h)*HP2 + row)*32 + u], u<16: K pair u, u>=16: V pair u-16.
// ---------------------------------------------------------------------------

// Kernel 1: fill padded borders of KVp with bias (= proj of zero input), and
// build PhiT: [B][102][102][16] fp32, border = 1.0
__global__ __launch_bounds__(256) void pad_fill(
    const float* __restrict__ phi, const float* __restrict__ bk, const float* __restrict__ bv,
    uint* __restrict__ KVp, float* __restrict__ PhiT)
{
    int idx = blockIdx.x * 256 + threadIdx.x;
    if (idx >= B_*HP2_) return;
    int b  = idx / HP2_;
    int pp = idx % HP2_;
    int py = pp / HP_, px = pp % HP_;
    bool interior = (py >= PAD_ && py < H_+PAD_ && px >= PAD_ && px < W_+PAD_);
    if (!interior) {
        #pragma unroll
        for (int h = 0; h < HEADS_; ++h) {
            size_t base = ((size_t)(b*HEADS_+h)*HP2_ + pp) * 32;
            #pragma unroll
            for (int q4i = 0; q4i < 4; ++q4i) {
                const float* kb8 = bk + h*HD_ + q4i*8;
                const float* vb8 = bv + h*HD_ + q4i*8;
                uint4 ku, vu;
                ku.x = pack2(kb8[0],kb8[1]); ku.y = pack2(kb8[2],kb8[3]);
                ku.z = pack2(kb8[4],kb8[5]); ku.w = pack2(kb8[6],kb8[7]);
                vu.x = pack2(vb8[0],vb8[1]); vu.y = pack2(vb8[2],vb8[3]);
                vu.z = pack2(vb8[4],vb8[5]); vu.w = pack2(vb8[6],vb8[7]);
                ((uint4*)(KVp + base))[q4i]     = ku;
                ((uint4*)(KVp + base))[4 + q4i] = vu;
            }
        }
    }
    size_t pb = ((size_t)b*HP2_ + pp) * M_;
    if (interior) {
        int y = py - PAD_, xx = px - PAD_;
        #pragma unroll
        for (int m = 0; m < M_; ++m)
            PhiT[pb + m] = phi[((size_t)b*M_ + m)*N_ + y*W_ + xx];
    } else {
        #pragma unroll
        for (int m = 0; m < M_; ++m) PhiT[pb + m] = 1.0f;
    }
}

// ---------------------------------------------------------------------------
// Kernel 2: Q/K/V projection on MFMA (16x16x32 bf16). (r15 exact.)
// ---------------------------------------------------------------------------
__global__ __launch_bounds__(256, 3) void qkv_proj(
    const float* __restrict__ x,
    const float* __restrict__ Wq, const float* __restrict__ bq,
    const float* __restrict__ Wk, const float* __restrict__ bk,
    const float* __restrict__ Wv, const float* __restrict__ bv,
    float* __restrict__ Qp, uint* __restrict__ KVp)
{
    __shared__ uint ldsA[128*64];   // W^T [co][ci2] bf16 pairs, swizzled (32 KB)
    __shared__ uint ldsB[64*64];    // x^T [pix][ci2] bf16 pairs, swizzled (16 KB)

    const int t  = threadIdx.x;
    const int n0 = blockIdx.x * 64;
    const int b  = blockIdx.y;
    const int pj = blockIdx.z;
    const float* Wsrc = (pj == 0) ? Wq : (pj == 1) ? Wk : Wv;
    const float* bsrc = (pj == 0) ? bq : (pj == 1) ? bk : bv;

    for (int idx = t; idx < 128*64; idx += 256) {
        int co = idx & 127, c2 = idx >> 7;
        float w0 = Wsrc[(size_t)(2*c2  )*C_ + co];
        float w1 = Wsrc[(size_t)(2*c2+1)*C_ + co];
        ldsA[co*64 + SWZ(co, c2)] = pack2(w0, w1);
    }
    const float* xb = x + (size_t)b*C_*N_;
    for (int idx = t; idx < 64*64; idx += 256) {
        int pix = idx & 63, c2 = idx >> 6;
        float a0 = xb[(size_t)(2*c2  )*N_ + n0 + pix];
        float a1 = xb[(size_t)(2*c2+1)*N_ + n0 + pix];
        ldsB[pix*64 + SWZ(pix, c2)] = pack2(a0, a1);
    }
    __syncthreads();

    const int lane = t & 63, w = t >> 6;
    const int q = lane >> 4, r16 = lane & 15;
    const int sw = (r16 & 7) << 2;

    f32x4 acc[2][4];
    #pragma unroll
    for (int cf = 0; cf < 2; ++cf) {
        float4 b4 = *(const float4*)(bsrc + (2*w+cf)*16 + q*4);
        f32x4 bi = {b4.x, b4.y, b4.z, b4.w};
        #pragma unroll
        for (int pf = 0; pf < 4; ++pf) acc[cf][pf] = bi;
    }

    #pragma unroll
    for (int kk = 0; kk < 4; ++kk) {
        int kbase = kk*16 + q*4;
        bf16x8 af[2], bfr[4];
        #pragma unroll
        for (int cf = 0; cf < 2; ++cf) {
            int row = (2*w+cf)*16 + r16;
            af[cf] = *(const bf16x8*)&ldsA[row*64 + (kbase ^ sw)];
        }
        #pragma unroll
        for (int pf = 0; pf < 4; ++pf) {
            int row = pf*16 + r16;
            bfr[pf] = *(const bf16x8*)&ldsB[row*64 + (kbase ^ sw)];
        }
        #pragma unroll
        for (int cf = 0; cf < 2; ++cf)
            #pragma unroll
            for (int pf = 0; pf < 4; ++pf)
                acc[cf][pf] = __builtin_amdgcn_mfma_f32_16x16x32_bf16(
                    af[cf], bfr[pf], acc[cf][pf], 0, 0, 0);
    }

    if (pj == 0) {
        #pragma unroll
        for (int pf = 0; pf < 4; ++pf) {
            int n = n0 + pf*16 + r16;
            #pragma unroll
            for (int cf = 0; cf < 2; ++cf) {
                int co0 = (2*w+cf)*16 + q*4;
                *(f32x4*)(Qp + ((size_t)b*N_ + n)*C_ + co0) = acc[cf][pf];
            }
        }
    } else {
        int rowb[4];
        #pragma unroll
        for (int pf = 0; pf < 4; ++pf) {
            int n = n0 + pf*16 + r16;
            int y = n / W_, xx = n - y*W_;
            rowb[pf] = (y+PAD_)*HP_ + xx + PAD_;
        }
        const int ubase = (pj == 1) ? 0 : 16;
        #pragma unroll
        for (int cf = 0; cf < 2; ++cf) {
            int co0 = (2*w+cf)*16 + q*4;
            int h   = co0 >> 5;
            int u   = ubase + ((co0 & 31) >> 1);
            uint* kvb = KVp + (size_t)(b*HEADS_+h)*HP2_*32;
            #pragma unroll
            for (int pf = 0; pf < 4; ++pf) {
                uint2 uu;
                uu.x = pack2(acc[cf][pf][0], acc[cf][pf][1]);
                uu.y = pack2(acc[cf][pf][2], acc[cf][pf][3]);
                *(uint2*)(kvb + (size_t)rowb[pf]*32 + u) = uu;
            }
        }
    }
}

// ---------------------------------------------------------------------------
// Kernel 3: local attention on MFMA, masked dense over the 14x16-padded halo.
// Block = (tile, h, b), 4 waves; wave w owns pixels w*16..w*16+15.
// QK^T: D[kv 224][pix 64] = k'[kv][64d] x q''[pix][64d]; k' = [K|phi|0],
// q'' = [scale*q | -2g*pc | 0] with q-side hi+lo bf16 compensation (2 chains).
// Geo: logit += g*|pv|^2 (fp32 post-add); g*|pc|^2 dropped (softmax-invariant).
// Mask: ky = kvfrag f (literal), kx = qq*4+r. P (normalized, bf16) goes to
// wave-private LDS rows -> A-operand of PV: D[pix][ch] = P[pix][kv] x V^T.
// LDS: 32KB k'/P union + 16KB V^T + 1KB pv2 = 49KB -> 3 blocks/CU.
// ---------------------------------------------------------------------------
__global__ __launch_bounds__(256, 3) void attn(
    const float* __restrict__ Qp, const uint* __restrict__ KVp,
    const float* __restrict__ PhiT, const float* __restrict__ log_alpha,
    const float* __restrict__ beta, float* __restrict__ AO)
{
    __shared__ uint  lds0[64*128];   // k' [224][32] then P [64][128] (32 KB)
    __shared__ uint  vtl[32*128];    // V^T [32 ch][112 kv2, pad 128] (16 KB)
    __shared__ float pv2l[224];      // g*|pv|^2 per kv row

    const int t  = threadIdx.x;
    const int h  = blockIdx.y;
    const int b  = blockIdx.z;
    const int bx = blockIdx.x;
    const int tile = ((bx & 7) * 18) + (bx >> 3);   // 144 = 8*18, bijective
    const int y0 = (tile / (W_/TILE_)) * TILE_;
    const int x0 = (tile % (W_/TILE_)) * TILE_;

    const float alpha = __expf(log_alpha[0]);
    const float scale = 0.17677669529663687f;                 // HD^-0.5
    const float gcoef = -beta[h] * alpha * 0.17677669529663687f; // -beta*alpha/sqrt(2M)

    const uint*  kvb = KVp + (size_t)(b*HEADS_+h)*HP2_*32;
    const float* phb = PhiT + (size_t)b*HP2_*M_;

    // ---- stage k' rows: [K pairs 16u | phi pairs 8u | zeros 8u], kx>=14 -> 0
    for (int idx = t; idx < 224*32; idx += 256) {
        int row = idx >> 5, colu = idx & 31;
        int ky = row >> 4, kx = row & 15;
        uint val = 0;
        if (kx < 14) {
            size_t rowb = (size_t)(y0+ky)*HP_ + (x0+kx);
            if (colu < 16) {
                val = kvb[rowb*32 + colu];
            } else if (colu < 24) {
                const float* pp = phb + rowb*M_ + (colu-16)*2;
                val = pack2(pp[0], pp[1]);
            }
        }
        lds0[row*32 + SWZ(row, colu)] = val;
    }
    // ---- stage V^T [ch][kv2]: transpose of KVp's per-row V pairs
    for (int idx = t; idx < 16*128; idx += 256) {
        int kv2 = idx & 127, p = idx >> 7;
        if (kv2 >= 112) continue;
        uint a = 0, c = 0;
        if ((kv2 & 7) != 7) {            // kx 14,15 junk -> 0
            int kv0 = kv2*2;
            int ky = kv0 >> 4, kx = kv0 & 15;
            size_t rowb = (size_t)(y0+ky)*HP_ + (x0+kx);
            a = kvb[rowb*32 + 16 + p];        // V pair p at kv row even
            c = kvb[rowb*32 + 48 + p];        // kv row odd (= rowb+1)
        }
        int ch0 = p*2;
        uint lo = (a & 0xffffu) | (c << 16);
        uint hi = (a >> 16) | (c & 0xffff0000u);
        vtl[ch0*128     + SWZ(ch0,   kv2)] = lo;
        vtl[(ch0+1)*128 + SWZ(ch0+1, kv2)] = hi;
    }
    // ---- stage g*|pv|^2
    for (int idx = t; idx < 224; idx += 256) {
        int ky = idx >> 4, kx = idx & 15;
        float s = 0.f;
        if (kx < 14) {
            const float* pp = phb + ((size_t)(y0+ky)*HP_ + (x0+kx))*M_;
            #pragma unroll
            for (int m4 = 0; m4 < 4; ++m4) {
                float4 v = ((const float4*)pp)[m4];
                s = fmaf(v.x,v.x, fmaf(v.y,v.y, fmaf(v.z,v.z, fmaf(v.w,v.w, s))));
            }
            s *= gcoef;
        }
        pv2l[idx] = s;
    }

    // ---- per-lane q'' B-operand fragments (registers; no LDS)
    const int lane = t & 63, w = t >> 6;
    const int qq = lane >> 4, r16 = lane & 15;
    const int pix = w*16 + r16, py = pix >> 3, px = pix & 7;
    const int n = (y0+py)*W_ + (x0+px);

    U4 Bh0, Bl0, Bh1, Bl1;
    {
        const float* qp = Qp + ((size_t)b*N_ + n)*C_ + h*HD_ + qq*8;
        float4 qa = ((const float4*)qp)[0];
        float4 qb = ((const float4*)qp)[1];
        float v[8] = {qa.x*scale, qa.y*scale, qa.z*scale, qa.w*scale,
                      qb.x*scale, qb.y*scale, qb.z*scale, qb.w*scale};
        #pragma unroll
        for (int i = 0; i < 4; ++i) {
            float a0 = v[2*i], a1 = v[2*i+1];
            float r0 = a0 - __uint_as_float(f2bf(a0) << 16);
            float r1 = a1 - __uint_as_float(f2bf(a1) << 16);
            Bh0.u[i] = pack2(a0, a1);
            Bl0.u[i] = pack2(r0, r1);
            Bh1.u[i] = 0u; Bl1.u[i] = 0u;
        }
        if (qq < 2) {
            const float* pcp = phb + ((size_t)(y0+py+PAD_)*HP_ + (x0+px+PAD_))*M_ + qq*8;
            const float m2g = -2.0f * gcoef;
            #pragma unroll
            for (int i = 0; i < 4; ++i) {
                float a0 = pcp[2*i]*m2g, a1 = pcp[2*i+1]*m2g;
                float r0 = a0 - __uint_as_float(f2bf(a0) << 16);
                float r1 = a1 - __uint_as_float(f2bf(a1) << 16);
                Bh1.u[i] = pack2(a0, a1);
                Bl1.u[i] = pack2(r0, r1);
            }
        }
    }
    __syncthreads();

    // ---- QK^T + geo: 14 kv-frags x (2 ksteps) x (hi+lo)
    const int sw = (r16 & 7) << 2;
    const int c0 = (qq*4) ^ sw;
    const int c1 = (16 + qq*4) ^ sw;

    float lp[56];
    float mx = -1e30f;
    #pragma unroll
    for (int f = 0; f < 14; ++f) {
        const uint* arow = lds0 + (f*16 + r16)*32;
        bf16x8 A0 = *(const bf16x8*)(arow + c0);
        bf16x8 A1 = *(const bf16x8*)(arow + c1);
        f32x4 ah = {0.f,0.f,0.f,0.f}, al = {0.f,0.f,0.f,0.f};
        ah = __builtin_amdgcn_mfma_f32_16x16x32_bf16(A0, Bh0.v, ah, 0,0,0);
        ah = __builtin_amdgcn_mfma_f32_16x16x32_bf16(A1, Bh1.v, ah, 0,0,0);
        al = __builtin_amdgcn_mfma_f32_16x16x32_bf16(A0, Bl0.v, al, 0,0,0);
        al = __builtin_amdgcn_mfma_f32_16x16x32_bf16(A1, Bl1.v, al, 0,0,0);
        #pragma unroll
        for (int r = 0; r < 4; ++r) {
            int kx = qq*4 + r;                       // ky = f (literal)
            float lg = ah[r] + al[r] + pv2l[f*16 + kx];
            bool ok = ((uint)(f - py) < 7u) && ((uint)(kx - px) < 7u);
            lg = ok ? lg : -1e30f;
            lp[f*4+r] = lg;
            mx = fmaxf(mx, lg);
        }
    }
    mx = fmaxf(mx, __shfl_xor(mx, 16));
    mx = fmaxf(mx, __shfl_xor(mx, 32));
    float ssum = 0.f;
    #pragma unroll
    for (int i = 0; i < 56; ++i) { float e = __expf(lp[i]-mx); lp[i] = e; ssum += e; }
    ssum += __shfl_xor(ssum, 16);
    ssum += __shfl_xor(ssum, 32);
    float inv = 1.0f / ssum;

    __syncthreads();   // all waves done reading k' -> overlay P in lds0

    // ---- P (normalized bf16) -> wave-private rows of lds0 [pix][kv2 pad128]
    uint* prow = lds0 + (size_t)pix*128;
    #pragma unroll
    for (int f = 0; f < 14; ++f) {
        uint u0 = pack2(lp[f*4+0]*inv, lp[f*4+1]*inv);
        uint u1 = pack2(lp[f*4+2]*inv, lp[f*4+3]*inv);
        *(uint2*)(prow + ((f*8 + qq*2) ^ sw)) = make_uint2(u0, u1);
    }

    // ---- PV: D[pix][ch] = P[pix][kv] x V[kv][ch], 2 ch-frags x 7 ksteps
    #pragma unroll
    for (int chf = 0; chf < 2; ++chf) {
        f32x4 acc = {0.f,0.f,0.f,0.f};
        const uint* vrow = vtl + (chf*16 + r16)*128;
        #pragma unroll
        for (int ks = 0; ks < 7; ++ks) {
            int kb = (ks*16 + qq*4) ^ sw;
            bf16x8 Af = *(const bf16x8*)(prow + kb);
            bf16x8 Bf = *(const bf16x8*)(vrow + kb);
            acc = __builtin_amdgcn_mfma_f32_16x16x32_bf16(Af, Bf, acc, 0,0,0);
        }
        #pragma unroll
        for (int r = 0; r < 4; ++r) {
            int pixr = w*16 + qq*4 + r;
            int nr = (y0 + (pixr>>3))*W_ + x0 + (pixr&7);
            AO[((size_t)b*N_ + nr)*C_ + h*HD_ + chf*16 + r16] = acc[r];
        }
    }
}

// ---------------------------------------------------------------------------
// Kernel 4: output projection on MFMA. (r15 exact.)
// ---------------------------------------------------------------------------
__global__ __launch_bounds__(256, 3) void out_proj(
    const float* __restrict__ AO, const float* __restrict__ Wo,
    const float* __restrict__ bo, float* __restrict__ out)
{
    __shared__ uint ldsA[128*64];   // Wo^T (32 KB)
    __shared__ uint ldsB[64*64];    // AO   (16 KB)

    const int t  = threadIdx.x;
    const int b  = blockIdx.x / (N_/64);
    const int n0 = (blockIdx.x % (N_/64)) * 64;

    for (int idx = t; idx < 128*64; idx += 256) {
        int co = idx & 127, c2 = idx >> 7;
        float w0 = Wo[(size_t)(2*c2  )*C_ + co];
        float w1 = Wo[(size_t)(2*c2+1)*C_ + co];
        ldsA[co*64 + SWZ(co, c2)] = pack2(w0, w1);
    }
    for (int idx = t; idx < 64*32; idx += 256) {
        int pix = idx >> 5, c4 = idx & 31;
        float4 v = ((const float4*)(AO + ((size_t)b*N_ + n0 + pix)*C_))[c4];
        ldsB[pix*64 + SWZ(pix, 2*c4  )] = pack2(v.x, v.y);
        ldsB[pix*64 + SWZ(pix, 2*c4+1)] = pack2(v.z, v.w);
    }
    __syncthreads();

    const int lane = t & 63, w = t >> 6;
    const int q = lane >> 4, r16 = lane & 15;
    const int sw = (r16 & 7) << 2;

    f32x4 acc[2][4];
    #pragma unroll
    for (int cf = 0; cf < 2; ++cf) {
        float4 b4 = *(const float4*)(bo + (2*w+cf)*16 + q*4);
        f32x4 bi = {b4.x, b4.y, b4.z, b4.w};
        #pragma unroll
        for (int pf = 0; pf < 4; ++pf) acc[cf][pf] = bi;
    }

    #pragma unroll
    for (int kk = 0; kk < 4; ++kk) {
        int kbase = kk*16 + q*4;
        bf16x8 af[2], bfr[4];
        #pragma unroll
        for (int cf = 0; cf < 2; ++cf) {
            int row = (2*w+cf)*16 + r16;
            af[cf] = *(const bf16x8*)&ldsA[row*64 + (kbase ^ sw)];
        }
        #pragma unroll
        for (int pf = 0; pf < 4; ++pf) {
            int row = pf*16 + r16;
            bfr[pf] = *(const bf16x8*)&ldsB[row*64 + (kbase ^ sw)];
        }
        #pragma unroll
        for (int cf = 0; cf < 2; ++cf)
            #pragma unroll
            for (int pf = 0; pf < 4; ++pf)
                acc[cf][pf] = __builtin_amdgcn_mfma_f32_16x16x32_bf16(
                    af[cf], bfr[pf], acc[cf][pf], 0, 0, 0);
    }

    #pragma unroll
    for (int cf = 0; cf < 2; ++cf) {
        #pragma unroll
        for (int rr = 0; rr < 4; ++rr) {
            int co = (2*w+cf)*16 + q*4 + rr;
            float* orow = out + ((size_t)b*C_ + co)*N_ + n0;
            #pragma unroll
            for (int pf = 0; pf < 4; ++pf)
                orow[pf*16 + r16] = acc[cf][pf][rr];
        }
    }
}

// ---------------------------------------------------------------------------
extern "C" void kernel_launch(void* const* d_in, const int* in_sizes, int n_in,
                              void* d_out, int out_size, void* d_ws, size_t ws_size,
                              hipStream_t stream)
{
    const float* x    = (const float*)d_in[0];
    const float* phi  = (const float*)d_in[1];
    const float* Wq   = (const float*)d_in[2];
    const float* bq   = (const float*)d_in[3];
    const float* Wk   = (const float*)d_in[4];
    const float* bk   = (const float*)d_in[5];
    const float* Wv   = (const float*)d_in[6];
    const float* bv   = (const float*)d_in[7];
    const float* Wo   = (const float*)d_in[8];
    const float* bo   = (const float*)d_in[9];
    const float* la   = (const float*)d_in[10];
    const float* beta = (const float*)d_in[11];
    float* out = (float*)d_out;

    // workspace layout. AO aliases Qp: wave-private pixel sets, reads-before-
    // writes within each wave, disjoint head slices across blocks.
    float* ws   = (float*)d_ws;
    float* Qp   = ws;                                        // 9.44 MB fp32
    uint*  KVp  = (uint*)(Qp + (size_t)B_*N_*C_);            // 10.65 MB
    float* PhiT = (float*)(KVp + (size_t)B_*HEADS_*HP2_*32); // 1.33 MB
    float* AO   = Qp;                                        // aliased

    pad_fill<<<dim3((B_*HP2_ + 255)/256), dim3(256), 0, stream>>>(phi, bk, bv, KVp, PhiT);
    qkv_proj<<<dim3(N_/64, B_, 3), dim3(256), 0, stream>>>(x, Wq, bq, Wk, bk, Wv, bv, Qp, KVp);
    attn<<<dim3((H_/TILE_)*(W_/TILE_), HEADS_, B_), dim3(256), 0, stream>>>(Qp, KVp, PhiT, la, beta, AO);
    out_proj<<<dim3(B_*(N_/64)), dim3(256), 0, stream>>>(AO, Wo, bo, out);
}